// Round 3
// baseline (456.555 us; speedup 1.0000x reference)
//
#include <hip/hip_runtime.h>
#include <cmath>

#define NB    64
#define TENC  1024
#define DENC  512
#define QDIM  1024
#define HDIM  256
#define NM    5
#define EPSF  1e-5f
#define SSPLIT 16
#define TCH   (TENC / SSPLIT)   // 64 t-rows per context block

// ws layout:
//   partial : [SSPLIT][NB][DENC] f32 = 2 MB   @ 0
//   stats   : [NB][16] f32               @ 2 MB
//   counter : [NB] int                   @ 2 MB + 4 KB
#define WS_PARTIAL_F 0
#define WS_STATS_F   (SSPLIT * NB * DENC)
#define WS_CNT_F     (WS_STATS_F + NB * 16)

// ---------------------------------------------------------------------------
// Kernel A: per-batch front end -> stats only.
//   h = relu(q @ W1 + b1); params = h @ W2 + b2
//   stats = { w=softmax(p[0:5])+eps, sigma=softplus(p[5:10])+eps,
//             mu=mu_prev+softplus(p[10:15]) }
// Also zeroes the per-batch counter used by kernel B's last-block reduce
// (d_ws is poisoned to 0xAA before every call; A runs before B in stream
// order, which gives a full memory sync between dispatches).
// One block per batch row, 256 threads.
// ---------------------------------------------------------------------------
__global__ __launch_bounds__(256) void mol_stats(
    const float* __restrict__ q,        // B x 1024
    const float* __restrict__ W1,       // 1024 x 256 (row-major)
    const float* __restrict__ b1,       // 256
    const float* __restrict__ W2,       // 256 x 15
    const float* __restrict__ b2,       // 15
    const float* __restrict__ mu_prev,  // B x 5
    float* __restrict__ stats_g,        // NB x 16
    int*   __restrict__ counter)        // NB
{
    __shared__ float  q_lds[QDIM];
    __shared__ float4 part[4][64];      // split-K partials for h
    __shared__ float  h_lds[HDIM];
    __shared__ float  p_part[15][16];   // split-K partials for params
    __shared__ float  p_lds[16];
    __shared__ float  stats[16];        // w[5], sigma[5], mu[5]

    const int b   = blockIdx.x;
    const int tid = threadIdx.x;

    // stage q row (4 KB) into LDS, float4-coalesced
    ((float4*)q_lds)[tid] = ((const float4*)(q + (size_t)b * QDIM))[tid];
    __syncthreads();

    // h = relu(q @ W1 + b1): thread = (g = k-group 0..3, c = output float4 0..63)
    const int g = tid >> 6;
    const int c = tid & 63;
    {
        const float4* W1v = (const float4*)W1;   // [k][64] float4
        float4 acc = make_float4(0.f, 0.f, 0.f, 0.f);
        const int k0 = g << 8;
        #pragma unroll 4
        for (int k = 0; k < 256; ++k) {
            const float  qk = q_lds[k0 + k];                    // wave-broadcast
            const float4 wv = W1v[(size_t)(k0 + k) * 64 + c];   // 1KB/wave coalesced
            acc.x = fmaf(qk, wv.x, acc.x);
            acc.y = fmaf(qk, wv.y, acc.y);
            acc.z = fmaf(qk, wv.z, acc.z);
            acc.w = fmaf(qk, wv.w, acc.w);
        }
        part[g][c] = acc;
    }
    __syncthreads();

    if (tid < 64) {
        const float4 s0 = part[0][tid], s1 = part[1][tid];
        const float4 s2 = part[2][tid], s3 = part[3][tid];
        const float4 bb = ((const float4*)b1)[tid];
        float4 h;
        h.x = fmaxf(s0.x + s1.x + s2.x + s3.x + bb.x, 0.f);
        h.y = fmaxf(s0.y + s1.y + s2.y + s3.y + bb.y, 0.f);
        h.z = fmaxf(s0.z + s1.z + s2.z + s3.z + bb.z, 0.f);
        h.w = fmaxf(s0.w + s1.w + s2.w + s3.w + bb.w, 0.f);
        ((float4*)h_lds)[tid] = h;
    }
    __syncthreads();

    // params = h @ W2 + b2 : 15 outputs x 16 k-groups of 16 (240 threads)
    if (tid < 240) {
        const int o  = tid >> 4;        // output 0..14
        const int kg = tid & 15;        // k-group 0..15
        float acc = 0.f;
        #pragma unroll
        for (int i = 0; i < 16; ++i) {
            const int k = kg * 16 + i;
            acc = fmaf(h_lds[k], W2[k * 15 + o], acc);
        }
        p_part[o][kg] = acc;
    }
    __syncthreads();
    if (tid < 15) {
        float acc = b2[tid];
        #pragma unroll
        for (int kg = 0; kg < 16; ++kg) acc += p_part[tid][kg];
        p_lds[tid] = acc;
    }
    __syncthreads();

    if (tid == 0) {
        // softmax over p[0:5]
        float mx = p_lds[0];
        #pragma unroll
        for (int m = 1; m < NM; ++m) mx = fmaxf(mx, p_lds[m]);
        float e[NM], se = 0.f;
        #pragma unroll
        for (int m = 0; m < NM; ++m) { e[m] = expf(p_lds[m] - mx); se += e[m]; }
        const float inv = 1.f / se;
        #pragma unroll
        for (int m = 0; m < NM; ++m) stats[m] = e[m] * inv + EPSF;
        // sigma = softplus + eps (stable softplus)
        #pragma unroll
        for (int m = 0; m < NM; ++m) {
            const float x = p_lds[NM + m];
            stats[NM + m] = fmaxf(x, 0.f) + log1pf(expf(-fabsf(x))) + EPSF;
        }
        // mu = mu_prev + softplus(Delta_hat)
        #pragma unroll
        for (int m = 0; m < NM; ++m) {
            const float x = p_lds[2 * NM + m];
            stats[2 * NM + m] = mu_prev[b * NM + m] + fmaxf(x, 0.f) + log1pf(expf(-fabsf(x)));
        }
        counter[b] = 0;                 // re-arm last-block flag every call
    }
    __syncthreads();

    if (tid < 15) stats_g[b * 16 + tid] = stats[tid];
}

// ---------------------------------------------------------------------------
// Kernel B: alpha + split-K context + last-block-per-batch reduce.
// Grid = B * SSPLIT blocks; block (b,s) owns t in [s*64, s*64+64):
//   1) threads 0..63 compute alpha[t] from stats (10 exps each), write the
//      chunk to d_out's alpha region and to LDS
//   2) all 256 threads stream the 128 KB memory chunk (float4-coalesced),
//      accumulate, write one partial row to ws
//   3) release-fence + counter atomic; the 16th block of batch b
//      acquire-fences, sums the 16 partials, writes context[b]
// ---------------------------------------------------------------------------
__global__ __launch_bounds__(256) void mol_ctx(
    const float* __restrict__ stats_g,  // NB x 16
    const float* __restrict__ memory,   // B x T x D
    const unsigned char* __restrict__ mask, // B x T
    float* __restrict__ alpha_out,      // B x T (in d_out)
    float* __restrict__ partial,        // SSPLIT x NB x DENC (ws)
    float* __restrict__ context,        // B x DENC (in d_out)
    int*   __restrict__ counter)        // NB (ws)
{
    __shared__ float  st[16];
    __shared__ float  a_lds[TCH];
    __shared__ float4 red[128];
    __shared__ int    is_last;

    const int b   = blockIdx.x >> 4;    // / SSPLIT
    const int s   = blockIdx.x & (SSPLIT - 1);
    const int tid = threadIdx.x;
    const int t0  = s * TCH;

    if (tid < 16) st[tid] = stats_g[b * 16 + tid];
    __syncthreads();

    if (tid < TCH) {
        const int t = t0 + tid;
        const float jA = (float)t + 0.5f;
        const float jB = (float)t + 1.5f;
        float FA = 0.f, FB = 0.f;
        #pragma unroll
        for (int m = 0; m < NM; ++m) {
            const float w   = st[m];
            const float isg = 1.f / st[NM + m];
            const float mu  = st[2 * NM + m];
            const float sA = 1.f / (1.f + expf(-(mu - jA) * isg));   // sigmoid
            const float sB = 1.f / (1.f + expf(-(mu - jB) * isg));
            FA += w / (1.f + sA);
            FB += w / (1.f + sB);
        }
        float a = FB - FA;
        if (a == 0.f) a = EPSF;                  // where(alpha==0, EPS)
        if (mask[(size_t)b * TENC + t]) a = 0.f; // where(mask, 0)
        a_lds[tid] = a;
        alpha_out[(size_t)b * TENC + t] = a;     // 256 B contiguous store
    }
    __syncthreads();

    const int dd = tid & 127;           // float4 column 0..127
    const int tt = tid >> 7;            // 0..1: two t-rows in flight
    const float4* mem4 = (const float4*)(memory + ((size_t)b * TENC + t0) * DENC);

    float4 acc = make_float4(0.f, 0.f, 0.f, 0.f);
    #pragma unroll 8
    for (int t = tt; t < TCH; t += 2) {
        const float  a  = a_lds[t];                 // wave-broadcast
        const float4 mv = mem4[(size_t)t * 128 + dd];
        acc.x = fmaf(a, mv.x, acc.x);
        acc.y = fmaf(a, mv.y, acc.y);
        acc.z = fmaf(a, mv.z, acc.z);
        acc.w = fmaf(a, mv.w, acc.w);
    }

    // combine tt halves in LDS, one coalesced float4 store per column
    if (tt == 1) red[dd] = acc;
    __syncthreads();
    if (tt == 0) {
        const float4 o = red[dd];
        acc.x += o.x; acc.y += o.y; acc.z += o.z; acc.w += o.w;
        ((float4*)(partial + ((size_t)s * NB + b) * DENC))[dd] = acc;
    }

    // --- last-block-per-batch reduction (threadfence-reduction pattern) ---
    __threadfence();                    // release partial stores (device scope)
    __syncthreads();
    if (tid == 0) is_last = (atomicAdd(&counter[b], 1) == SSPLIT - 1);
    __syncthreads();

    if (is_last) {
        __threadfence();                // acquire: others' partials visible
        if (tid < 128) {
            const float4* p4 = (const float4*)partial;
            float4 r = make_float4(0.f, 0.f, 0.f, 0.f);
            #pragma unroll
            for (int s2 = 0; s2 < SSPLIT; ++s2) {
                const float4 v = p4[((size_t)s2 * NB + b) * 128 + tid];
                r.x += v.x; r.y += v.y; r.z += v.z; r.w += v.w;
            }
            ((float4*)(context + (size_t)b * DENC))[tid] = r;
        }
    }
}

extern "C" void kernel_launch(void* const* d_in, const int* in_sizes, int n_in,
                              void* d_out, int out_size, void* d_ws, size_t ws_size,
                              hipStream_t stream) {
    const float*         q       = (const float*)d_in[0];          // att_rnn_h (64,1024)
    const float*         memory  = (const float*)d_in[1];          // (64,1024,512)
    const unsigned char* mask    = (const unsigned char*)d_in[2];  // bool (64,1024)
    const float*         mu_prev = (const float*)d_in[3];          // (64,5)
    const float*         W1      = (const float*)d_in[4];          // (1024,256)
    const float*         b1      = (const float*)d_in[5];          // (256,)
    const float*         W2      = (const float*)d_in[6];          // (256,15)
    const float*         b2      = (const float*)d_in[7];          // (15,)

    float* out     = (float*)d_out;
    float* ctx     = out;                  // context: first 64*512 floats
    float* alpha   = out + NB * DENC;      // alpha_t: next 64*1024 floats
    float* ws_f    = (float*)d_ws;
    float* part    = ws_f + WS_PARTIAL_F;
    float* stats_g = ws_f + WS_STATS_F;
    int*   cnt     = (int*)(ws_f + WS_CNT_F);

    mol_stats<<<NB, 256, 0, stream>>>(q, W1, b1, W2, b2, mu_prev, stats_g, cnt);
    mol_ctx<<<NB * SSPLIT, 256, 0, stream>>>(stats_g, memory, mask, alpha, part, ctx, cnt);
}

// Round 4
// 244.141 us; speedup vs baseline: 1.8701x; 1.8701x over previous
//
#include <hip/hip_runtime.h>
#include <cmath>

#define NB    64
#define TENC  1024
#define DENC  512
#define QDIM  1024
#define HDIM  256
#define NM    5
#define EPSF  1e-5f
#define DCH   128                 // d-columns per context block
#define NDCH  (DENC / DCH)        // 4 d-chunks -> 64*4 = 256 blocks = 1/CU

// ---------------------------------------------------------------------------
// Kernel A: per-batch front end -> 15 stats per batch.
//   h = relu(q @ W1 + b1); params = h @ W2 + b2
//   stats = { w=softmax(p[0:5])+eps, sigma=softplus(p[5:10])+eps,
//             mu=mu_prev+softplus(p[10:15]) }
// One block per batch row, 256 threads. W1 (1 MB) is L2/LLC-resident.
// NO fences, NO atomics (R3 lesson: device-scope __threadfence on gfx950
// emits full-L2 writeback -> 288us stall; never again in a hot path).
// ---------------------------------------------------------------------------
__global__ __launch_bounds__(256) void mol_stats(
    const float* __restrict__ q,        // B x 1024
    const float* __restrict__ W1,       // 1024 x 256 (row-major)
    const float* __restrict__ b1,       // 256
    const float* __restrict__ W2,       // 256 x 15
    const float* __restrict__ b2,       // 15
    const float* __restrict__ mu_prev,  // B x 5
    float* __restrict__ stats_g)        // NB x 16
{
    __shared__ float  q_lds[QDIM];
    __shared__ float4 part[4][64];      // split-K partials for h
    __shared__ float  h_lds[HDIM];
    __shared__ float  p_part[15][16];   // split-K partials for params
    __shared__ float  p_lds[16];
    __shared__ float  stats[16];        // w[5], sigma[5], mu[5]

    const int b   = blockIdx.x;
    const int tid = threadIdx.x;

    // stage q row (4 KB) into LDS, float4-coalesced
    ((float4*)q_lds)[tid] = ((const float4*)(q + (size_t)b * QDIM))[tid];
    __syncthreads();

    // h = relu(q @ W1 + b1): thread = (g = k-group 0..3, c = output float4 0..63)
    const int g = tid >> 6;
    const int c = tid & 63;
    {
        const float4* W1v = (const float4*)W1;   // [k][64] float4
        float4 acc = make_float4(0.f, 0.f, 0.f, 0.f);
        const int k0 = g << 8;
        #pragma unroll 4
        for (int k = 0; k < 256; ++k) {
            const float  qk = q_lds[k0 + k];                    // wave-broadcast
            const float4 wv = W1v[(size_t)(k0 + k) * 64 + c];   // 1KB/wave coalesced
            acc.x = fmaf(qk, wv.x, acc.x);
            acc.y = fmaf(qk, wv.y, acc.y);
            acc.z = fmaf(qk, wv.z, acc.z);
            acc.w = fmaf(qk, wv.w, acc.w);
        }
        part[g][c] = acc;
    }
    __syncthreads();

    if (tid < 64) {
        const float4 s0 = part[0][tid], s1 = part[1][tid];
        const float4 s2 = part[2][tid], s3 = part[3][tid];
        const float4 bb = ((const float4*)b1)[tid];
        float4 h;
        h.x = fmaxf(s0.x + s1.x + s2.x + s3.x + bb.x, 0.f);
        h.y = fmaxf(s0.y + s1.y + s2.y + s3.y + bb.y, 0.f);
        h.z = fmaxf(s0.z + s1.z + s2.z + s3.z + bb.z, 0.f);
        h.w = fmaxf(s0.w + s1.w + s2.w + s3.w + bb.w, 0.f);
        ((float4*)h_lds)[tid] = h;
    }
    __syncthreads();

    // params = h @ W2 + b2 : 15 outputs x 16 k-groups of 16 (240 threads)
    if (tid < 240) {
        const int o  = tid >> 4;        // output 0..14
        const int kg = tid & 15;        // k-group 0..15
        float acc = 0.f;
        #pragma unroll
        for (int i = 0; i < 16; ++i) {
            const int k = kg * 16 + i;
            acc = fmaf(h_lds[k], W2[k * 15 + o], acc);
        }
        p_part[o][kg] = acc;
    }
    __syncthreads();
    if (tid < 15) {
        float acc = b2[tid];
        #pragma unroll
        for (int kg = 0; kg < 16; ++kg) acc += p_part[tid][kg];
        p_lds[tid] = acc;
    }
    __syncthreads();

    if (tid == 0) {
        // softmax over p[0:5]
        float mx = p_lds[0];
        #pragma unroll
        for (int m = 1; m < NM; ++m) mx = fmaxf(mx, p_lds[m]);
        float e[NM], se = 0.f;
        #pragma unroll
        for (int m = 0; m < NM; ++m) { e[m] = expf(p_lds[m] - mx); se += e[m]; }
        const float inv = 1.f / se;
        #pragma unroll
        for (int m = 0; m < NM; ++m) stats[m] = e[m] * inv + EPSF;
        // sigma = softplus + eps (stable softplus)
        #pragma unroll
        for (int m = 0; m < NM; ++m) {
            const float x = p_lds[NM + m];
            stats[NM + m] = fmaxf(x, 0.f) + log1pf(expf(-fabsf(x))) + EPSF;
        }
        // mu = mu_prev + softplus(Delta_hat)
        #pragma unroll
        for (int m = 0; m < NM; ++m) {
            const float x = p_lds[2 * NM + m];
            stats[2 * NM + m] = mu_prev[b * NM + m] + fmaxf(x, 0.f) + log1pf(expf(-fabsf(x)));
        }
    }
    __syncthreads();

    if (tid < 15) stats_g[b * 16 + tid] = stats[tid];
}

// ---------------------------------------------------------------------------
// Kernel B: alpha (recomputed per block, LDS) + context over a D-chunk.
// Grid = NB * NDCH = 256 blocks (1 per CU), 512 threads (8 waves/CU).
// Block (b, dch) owns context[b, dch*128 : dch*128+128]:
//   1) compute alpha[b, 0..1023] from the 15 stats into LDS
//      (dch==0 block also writes alpha to d_out)
//   2) stream memory[b, :, d0:d0+128] (512 KB), 16 t-rows in flight,
//      512 B contiguous per 32 lanes, accumulate float4 in registers
//   3) 16-way LDS reduction, one float4 store per d-column
// Fully in-block: no ws, no atomics, no fences, no extra dispatch.
// ---------------------------------------------------------------------------
__global__ __launch_bounds__(512) void mol_ctx(
    const float* __restrict__ stats_g,  // NB x 16
    const float* __restrict__ memory,   // B x T x D
    const unsigned char* __restrict__ mask, // B x T
    float* __restrict__ alpha_out,      // B x T (in d_out)
    float* __restrict__ context)        // B x DENC (in d_out)
{
    __shared__ float  st[16];
    __shared__ float  a_lds[TENC];         // 4 KB
    __shared__ float4 red[16 * 32];        // 8 KB

    const int b   = blockIdx.x >> 2;       // / NDCH
    const int dch = blockIdx.x & (NDCH - 1);
    const int tid = threadIdx.x;
    const int d0  = dch * DCH;

    if (tid < 16) st[tid] = stats_g[b * 16 + tid];
    __syncthreads();

    // alpha: 2 t-values per thread
    #pragma unroll
    for (int i = 0; i < 2; ++i) {
        const int t = tid + i * 512;
        const float jA = (float)t + 0.5f;
        const float jB = (float)t + 1.5f;
        float FA = 0.f, FB = 0.f;
        #pragma unroll
        for (int m = 0; m < NM; ++m) {
            const float w   = st[m];
            const float isg = 1.f / st[NM + m];
            const float mu  = st[2 * NM + m];
            const float sA = 1.f / (1.f + expf(-(mu - jA) * isg));   // sigmoid
            const float sB = 1.f / (1.f + expf(-(mu - jB) * isg));
            FA += w / (1.f + sA);
            FB += w / (1.f + sB);
        }
        float a = FB - FA;
        if (a == 0.f) a = EPSF;                  // where(alpha==0, EPS)
        if (mask[(size_t)b * TENC + t]) a = 0.f; // where(mask, 0)
        a_lds[t] = a;
        if (dch == 0) alpha_out[(size_t)b * TENC + t] = a;  // coalesced
    }
    __syncthreads();

    // stream this block's 512 KB slice: thread = (tt = t-phase 0..15,
    // dc = float4 column 0..31). Per wave: 2 rows x 512 B contiguous.
    const int dc = tid & 31;
    const int tt = tid >> 5;
    const float4* mem4 = (const float4*)(memory + (size_t)b * TENC * DENC)
                         + (d0 >> 2) + dc;

    float4 acc = make_float4(0.f, 0.f, 0.f, 0.f);
    #pragma unroll 8
    for (int t = tt; t < TENC; t += 16) {
        const float  a  = a_lds[t];              // 2 bcast addrs/wave, no conflict
        const float4 mv = mem4[(size_t)t * (DENC / 4)];
        acc.x = fmaf(a, mv.x, acc.x);
        acc.y = fmaf(a, mv.y, acc.y);
        acc.z = fmaf(a, mv.z, acc.z);
        acc.w = fmaf(a, mv.w, acc.w);
    }

    // 16-way reduction per d-column (once per kernel; conflicts negligible)
    red[tt * 32 + dc] = acc;
    __syncthreads();
    if (tid < 32) {
        float4 r = red[tid];
        #pragma unroll
        for (int s = 1; s < 16; ++s) {
            const float4 v = red[s * 32 + tid];
            r.x += v.x; r.y += v.y; r.z += v.z; r.w += v.w;
        }
        ((float4*)(context + (size_t)b * DENC + d0))[tid] = r;
    }
}

extern "C" void kernel_launch(void* const* d_in, const int* in_sizes, int n_in,
                              void* d_out, int out_size, void* d_ws, size_t ws_size,
                              hipStream_t stream) {
    const float*         q       = (const float*)d_in[0];          // att_rnn_h (64,1024)
    const float*         memory  = (const float*)d_in[1];          // (64,1024,512)
    const unsigned char* mask    = (const unsigned char*)d_in[2];  // bool (64,1024)
    const float*         mu_prev = (const float*)d_in[3];          // (64,5)
    const float*         W1      = (const float*)d_in[4];          // (1024,256)
    const float*         b1      = (const float*)d_in[5];          // (256,)
    const float*         W2      = (const float*)d_in[6];          // (256,15)
    const float*         b2      = (const float*)d_in[7];          // (15,)

    float* out     = (float*)d_out;
    float* ctx     = out;                  // context: first 64*512 floats
    float* alpha   = out + NB * DENC;      // alpha_t: next 64*1024 floats
    float* stats_g = (float*)d_ws;         // 64*16 floats

    mol_stats<<<NB, 256, 0, stream>>>(q, W1, b1, W2, b2, mu_prev, stats_g);
    mol_ctx<<<NB * NDCH, 512, 0, stream>>>(stats_g, memory, mask, alpha, ctx);
}

// Round 5
// 227.392 us; speedup vs baseline: 2.0078x; 1.0737x over previous
//
#include <hip/hip_runtime.h>
#include <cmath>

#define NB    64
#define TENC  1024
#define DENC  512
#define QDIM  1024
#define HDIM  256
#define NM    5
#define EPSF  1e-5f
#define DCH   128                 // d-columns per context block
#define NDCH  (DENC / DCH)        // 4 d-chunks -> 64*4 = 256 blocks = 1/CU

// ---------------------------------------------------------------------------
// Single fused kernel. Grid = NB * NDCH = 256 blocks (1/CU), 512 threads.
// Block (b, dch) owns context[b, dch*128 : dch*128+128]:
//   0) redundantly (4x/batch) computes the front end:
//        h = relu(q@W1+b1)  -- 8-way split-K, W1 is a 1 MB L2-broadcast
//        p = h@W2+b2; stats = {softmax(p[0:5])+eps, softplus(p[5:10])+eps,
//                              mu_prev+softplus(p[10:15])}
//      (R3 lesson: redundant compute beats cross-block fences on gfx950 --
//       device-scope __threadfence emits full-L2 writeback, 288us stall)
//   1) alpha[b, 0..1023] from stats into LDS; dch==0 block writes it to d_out
//   2) streams memory[b, :, d0:d0+128] (512 KB), float4-coalesced,
//      16 t-rows in flight, register accumulate
//   3) 16-way LDS reduction, one float4 store per d-column
// No ws, no atomics, no fences, ONE dispatch.
// ---------------------------------------------------------------------------
__global__ __launch_bounds__(512) void mol_fused(
    const float* __restrict__ q,        // B x 1024
    const float* __restrict__ W1,       // 1024 x 256 (row-major)
    const float* __restrict__ b1,       // 256
    const float* __restrict__ W2,       // 256 x 15
    const float* __restrict__ b2,       // 15
    const float* __restrict__ mu_prev,  // B x 5
    const float* __restrict__ memory,   // B x T x D
    const unsigned char* __restrict__ mask, // B x T
    float* __restrict__ alpha_out,      // B x T (in d_out)
    float* __restrict__ context)        // B x DENC (in d_out)
{
    __shared__ float  q_lds[QDIM];         // 4 KB
    __shared__ float4 part8[8][64];        // 8 KB  (split-K partials for h)
    __shared__ float  h_lds[HDIM];         // 1 KB
    __shared__ float  p_part[15][16];      // split-K partials for params
    __shared__ float  p_lds[16];
    __shared__ float  stats[16];           // w[5], sigma[5], mu[5]
    __shared__ float  a_lds[TENC];         // 4 KB
    __shared__ float4 red[16 * 32];        // 8 KB

    const int b   = blockIdx.x >> 2;       // / NDCH
    const int dch = blockIdx.x & (NDCH - 1);
    const int tid = threadIdx.x;
    const int d0  = dch * DCH;

    // ---- stage q row (4 KB), float4-coalesced ----
    if (tid < 256)
        ((float4*)q_lds)[tid] = ((const float4*)(q + (size_t)b * QDIM))[tid];
    __syncthreads();

    // ---- h = relu(q @ W1 + b1): (g = k-group 0..7, c = output float4 0..63)
    {
        const int g = tid >> 6;
        const int c = tid & 63;
        const float4* W1v = (const float4*)W1;   // [k][64] float4
        float4 acc = make_float4(0.f, 0.f, 0.f, 0.f);
        const int k0 = g << 7;                   // 128 k-rows per group
        #pragma unroll 4
        for (int k = 0; k < 128; ++k) {
            const float  qk = q_lds[k0 + k];                    // wave-broadcast
            const float4 wv = W1v[(size_t)(k0 + k) * 64 + c];   // 1KB/wave coalesced
            acc.x = fmaf(qk, wv.x, acc.x);
            acc.y = fmaf(qk, wv.y, acc.y);
            acc.z = fmaf(qk, wv.z, acc.z);
            acc.w = fmaf(qk, wv.w, acc.w);
        }
        part8[g][c] = acc;
    }
    __syncthreads();

    if (tid < 64) {
        float4 s = part8[0][tid];
        #pragma unroll
        for (int g = 1; g < 8; ++g) {
            const float4 v = part8[g][tid];
            s.x += v.x; s.y += v.y; s.z += v.z; s.w += v.w;
        }
        const float4 bb = ((const float4*)b1)[tid];
        float4 h;
        h.x = fmaxf(s.x + bb.x, 0.f);
        h.y = fmaxf(s.y + bb.y, 0.f);
        h.z = fmaxf(s.z + bb.z, 0.f);
        h.w = fmaxf(s.w + bb.w, 0.f);
        ((float4*)h_lds)[tid] = h;
    }
    __syncthreads();

    // ---- params = h @ W2 + b2 : 15 outputs x 16 k-groups of 16 ----
    if (tid < 240) {
        const int o  = tid >> 4;        // output 0..14
        const int kg = tid & 15;        // k-group 0..15
        float acc = 0.f;
        #pragma unroll
        for (int i = 0; i < 16; ++i) {
            const int k = kg * 16 + i;
            acc = fmaf(h_lds[k], W2[k * 15 + o], acc);
        }
        p_part[o][kg] = acc;
    }
    __syncthreads();
    if (tid < 15) {
        float acc = b2[tid];
        #pragma unroll
        for (int kg = 0; kg < 16; ++kg) acc += p_part[tid][kg];
        p_lds[tid] = acc;
    }
    __syncthreads();

    // ---- stats ----
    if (tid == 0) {
        float mx = p_lds[0];
        #pragma unroll
        for (int m = 1; m < NM; ++m) mx = fmaxf(mx, p_lds[m]);
        float e[NM], se = 0.f;
        #pragma unroll
        for (int m = 0; m < NM; ++m) { e[m] = expf(p_lds[m] - mx); se += e[m]; }
        const float inv = 1.f / se;
        #pragma unroll
        for (int m = 0; m < NM; ++m) stats[m] = e[m] * inv + EPSF;
        #pragma unroll
        for (int m = 0; m < NM; ++m) {      // sigma = softplus + eps (stable)
            const float x = p_lds[NM + m];
            stats[NM + m] = fmaxf(x, 0.f) + log1pf(expf(-fabsf(x))) + EPSF;
        }
        #pragma unroll
        for (int m = 0; m < NM; ++m) {      // mu = mu_prev + softplus(Delta)
            const float x = p_lds[2 * NM + m];
            stats[2 * NM + m] = mu_prev[b * NM + m] + fmaxf(x, 0.f) + log1pf(expf(-fabsf(x)));
        }
    }
    __syncthreads();

    // ---- alpha: 2 t-values per thread ----
    #pragma unroll
    for (int i = 0; i < 2; ++i) {
        const int t = tid + i * 512;
        const float jA = (float)t + 0.5f;
        const float jB = (float)t + 1.5f;
        float FA = 0.f, FB = 0.f;
        #pragma unroll
        for (int m = 0; m < NM; ++m) {
            const float w   = stats[m];
            const float isg = 1.f / stats[NM + m];
            const float mu  = stats[2 * NM + m];
            const float sA = 1.f / (1.f + expf(-(mu - jA) * isg));   // sigmoid
            const float sB = 1.f / (1.f + expf(-(mu - jB) * isg));
            FA += w / (1.f + sA);
            FB += w / (1.f + sB);
        }
        float a = FB - FA;
        if (a == 0.f) a = EPSF;                  // where(alpha==0, EPS)
        if (mask[(size_t)b * TENC + t]) a = 0.f; // where(mask, 0)
        a_lds[t] = a;
        if (dch == 0) alpha_out[(size_t)b * TENC + t] = a;  // coalesced
    }
    __syncthreads();

    // ---- stream this block's 512 KB slice: (tt = t-phase 0..15,
    //      dc = float4 column 0..31); per wave: 2 rows x 512 B contiguous ----
    const int dc = tid & 31;
    const int tt = tid >> 5;
    const float4* mem4 = (const float4*)(memory + (size_t)b * TENC * DENC)
                         + (d0 >> 2) + dc;

    float4 acc = make_float4(0.f, 0.f, 0.f, 0.f);
    #pragma unroll 8
    for (int t = tt; t < TENC; t += 16) {
        const float  a  = a_lds[t];              // 2 bcast addrs/wave, no conflict
        const float4 mv = mem4[(size_t)t * (DENC / 4)];
        acc.x = fmaf(a, mv.x, acc.x);
        acc.y = fmaf(a, mv.y, acc.y);
        acc.z = fmaf(a, mv.z, acc.z);
        acc.w = fmaf(a, mv.w, acc.w);
    }

    // ---- 16-way reduction per d-column, one float4 store per column ----
    red[tt * 32 + dc] = acc;
    __syncthreads();
    if (tid < 32) {
        float4 r = red[tid];
        #pragma unroll
        for (int s = 1; s < 16; ++s) {
            const float4 v = red[s * 32 + tid];
            r.x += v.x; r.y += v.y; r.z += v.z; r.w += v.w;
        }
        ((float4*)(context + (size_t)b * DENC + d0))[tid] = r;
    }
}

extern "C" void kernel_launch(void* const* d_in, const int* in_sizes, int n_in,
                              void* d_out, int out_size, void* d_ws, size_t ws_size,
                              hipStream_t stream) {
    const float*         q       = (const float*)d_in[0];          // att_rnn_h (64,1024)
    const float*         memory  = (const float*)d_in[1];          // (64,1024,512)
    const unsigned char* mask    = (const unsigned char*)d_in[2];  // bool (64,1024)
    const float*         mu_prev = (const float*)d_in[3];          // (64,5)
    const float*         W1      = (const float*)d_in[4];          // (1024,256)
    const float*         b1      = (const float*)d_in[5];          // (256,)
    const float*         W2      = (const float*)d_in[6];          // (256,15)
    const float*         b2      = (const float*)d_in[7];          // (15,)

    float* out   = (float*)d_out;
    float* ctx   = out;                  // context: first 64*512 floats
    float* alpha = out + NB * DENC;      // alpha_t: next 64*1024 floats

    mol_fused<<<NB * NDCH, 512, 0, stream>>>(q, W1, b1, W2, b2, mu_prev,
                                             memory, mask, alpha, ctx);
}

// Round 6
// 225.860 us; speedup vs baseline: 2.0214x; 1.0068x over previous
//
#include <hip/hip_runtime.h>
#include <cmath>

#define NB    64
#define TENC  1024
#define DENC  512
#define QDIM  1024
#define HDIM  256
#define NM    5
#define EPSF  1e-5f
#define DCH   128                 // d-columns per context block
#define NDCH  (DENC / DCH)        // 4 d-chunks -> 64*4 = 256 blocks = 1/CU

// ---------------------------------------------------------------------------
// Single fused kernel. Grid = NB * NDCH = 256 blocks (1/CU), 512 threads.
// Block (b, dch) owns context[b, dch*128 : dch*128+128].
// R6 change (single variable): per-batch t-phase offset in the stream loop.
//   R5 evidence: 937 GB/s HBM, VALU 7.3% -> channel camping: all blocks swept
//   t in lockstep, so the instantaneous footprint was 64 x 2KB clusters at
//   exactly 2MB spacing == same channel subset for the whole GPU. tshift=b*16
//   spreads the 64 batches uniformly over the 1024 rows; dch-siblings stay
//   in-phase so each 2KB row is covered contiguously.
// (R3 lesson stands: no fences/atomics anywhere.)
// ---------------------------------------------------------------------------
__global__ __launch_bounds__(512) void mol_fused(
    const float* __restrict__ q,        // B x 1024
    const float* __restrict__ W1,       // 1024 x 256 (row-major)
    const float* __restrict__ b1,       // 256
    const float* __restrict__ W2,       // 256 x 15
    const float* __restrict__ b2,       // 15
    const float* __restrict__ mu_prev,  // B x 5
    const float* __restrict__ memory,   // B x T x D
    const unsigned char* __restrict__ mask, // B x T
    float* __restrict__ alpha_out,      // B x T (in d_out)
    float* __restrict__ context)        // B x DENC (in d_out)
{
    __shared__ float  q_lds[QDIM];         // 4 KB
    __shared__ float4 part8[8][64];        // 8 KB  (split-K partials for h)
    __shared__ float  h_lds[HDIM];         // 1 KB
    __shared__ float  p_part[15][16];      // split-K partials for params
    __shared__ float  p_lds[16];
    __shared__ float  stats[16];           // w[5], sigma[5], mu[5]
    __shared__ float  a_lds[TENC];         // 4 KB
    __shared__ float4 red[16 * 32];        // 8 KB

    const int b   = blockIdx.x >> 2;       // / NDCH
    const int dch = blockIdx.x & (NDCH - 1);
    const int tid = threadIdx.x;
    const int d0  = dch * DCH;

    // ---- stage q row (4 KB), float4-coalesced ----
    if (tid < 256)
        ((float4*)q_lds)[tid] = ((const float4*)(q + (size_t)b * QDIM))[tid];
    __syncthreads();

    // ---- h = relu(q @ W1 + b1): (g = k-group 0..7, c = output float4 0..63)
    {
        const int g = tid >> 6;
        const int c = tid & 63;
        const float4* W1v = (const float4*)W1;   // [k][64] float4
        float4 acc = make_float4(0.f, 0.f, 0.f, 0.f);
        const int k0 = g << 7;                   // 128 k-rows per group
        #pragma unroll 4
        for (int k = 0; k < 128; ++k) {
            const float  qk = q_lds[k0 + k];                    // wave-broadcast
            const float4 wv = W1v[(size_t)(k0 + k) * 64 + c];   // 1KB/wave coalesced
            acc.x = fmaf(qk, wv.x, acc.x);
            acc.y = fmaf(qk, wv.y, acc.y);
            acc.z = fmaf(qk, wv.z, acc.z);
            acc.w = fmaf(qk, wv.w, acc.w);
        }
        part8[g][c] = acc;
    }
    __syncthreads();

    if (tid < 64) {
        float4 s = part8[0][tid];
        #pragma unroll
        for (int g = 1; g < 8; ++g) {
            const float4 v = part8[g][tid];
            s.x += v.x; s.y += v.y; s.z += v.z; s.w += v.w;
        }
        const float4 bb = ((const float4*)b1)[tid];
        float4 h;
        h.x = fmaxf(s.x + bb.x, 0.f);
        h.y = fmaxf(s.y + bb.y, 0.f);
        h.z = fmaxf(s.z + bb.z, 0.f);
        h.w = fmaxf(s.w + bb.w, 0.f);
        ((float4*)h_lds)[tid] = h;
    }
    __syncthreads();

    // ---- params = h @ W2 + b2 : 15 outputs x 16 k-groups of 16 ----
    if (tid < 240) {
        const int o  = tid >> 4;        // output 0..14
        const int kg = tid & 15;        // k-group 0..15
        float acc = 0.f;
        #pragma unroll
        for (int i = 0; i < 16; ++i) {
            const int k = kg * 16 + i;
            acc = fmaf(h_lds[k], W2[k * 15 + o], acc);
        }
        p_part[o][kg] = acc;
    }
    __syncthreads();
    if (tid < 15) {
        float acc = b2[tid];
        #pragma unroll
        for (int kg = 0; kg < 16; ++kg) acc += p_part[tid][kg];
        p_lds[tid] = acc;
    }
    __syncthreads();

    // ---- stats ----
    if (tid == 0) {
        float mx = p_lds[0];
        #pragma unroll
        for (int m = 1; m < NM; ++m) mx = fmaxf(mx, p_lds[m]);
        float e[NM], se = 0.f;
        #pragma unroll
        for (int m = 0; m < NM; ++m) { e[m] = expf(p_lds[m] - mx); se += e[m]; }
        const float inv = 1.f / se;
        #pragma unroll
        for (int m = 0; m < NM; ++m) stats[m] = e[m] * inv + EPSF;
        #pragma unroll
        for (int m = 0; m < NM; ++m) {      // sigma = softplus + eps (stable)
            const float x = p_lds[NM + m];
            stats[NM + m] = fmaxf(x, 0.f) + log1pf(expf(-fabsf(x))) + EPSF;
        }
        #pragma unroll
        for (int m = 0; m < NM; ++m) {      // mu = mu_prev + softplus(Delta)
            const float x = p_lds[2 * NM + m];
            stats[2 * NM + m] = mu_prev[b * NM + m] + fmaxf(x, 0.f) + log1pf(expf(-fabsf(x)));
        }
    }
    __syncthreads();

    // ---- alpha: 2 t-values per thread ----
    #pragma unroll
    for (int i = 0; i < 2; ++i) {
        const int t = tid + i * 512;
        const float jA = (float)t + 0.5f;
        const float jB = (float)t + 1.5f;
        float FA = 0.f, FB = 0.f;
        #pragma unroll
        for (int m = 0; m < NM; ++m) {
            const float w   = stats[m];
            const float isg = 1.f / stats[NM + m];
            const float mu  = stats[2 * NM + m];
            const float sA = 1.f / (1.f + expf(-(mu - jA) * isg));   // sigmoid
            const float sB = 1.f / (1.f + expf(-(mu - jB) * isg));
            FA += w / (1.f + sA);
            FB += w / (1.f + sB);
        }
        float a = FB - FA;
        if (a == 0.f) a = EPSF;                  // where(alpha==0, EPS)
        if (mask[(size_t)b * TENC + t]) a = 0.f; // where(mask, 0)
        a_lds[t] = a;
        if (dch == 0) alpha_out[(size_t)b * TENC + t] = a;  // coalesced
    }
    __syncthreads();

    // ---- stream this block's 512 KB slice: (tt = t-phase 0..15,
    //      dc = float4 column 0..31); per wave: 2 rows x 512 B contiguous.
    //      t-order rotated by tshift = b*16 to kill cross-block channel
    //      camping (see header comment). ----
    const int dc = tid & 31;
    const int tt = tid >> 5;
    const int tshift = b << 4;                   // per-batch phase offset
    const float4* mem4 = (const float4*)(memory + (size_t)b * TENC * DENC)
                         + (d0 >> 2) + dc;

    float4 acc = make_float4(0.f, 0.f, 0.f, 0.f);
    #pragma unroll 8
    for (int i = tt; i < TENC; i += 16) {
        const int t = (i + tshift) & (TENC - 1);
        const float  a  = a_lds[t];              // 2 bcast addrs/wave, no conflict
        const float4 mv = mem4[(size_t)t * (DENC / 4)];
        acc.x = fmaf(a, mv.x, acc.x);
        acc.y = fmaf(a, mv.y, acc.y);
        acc.z = fmaf(a, mv.z, acc.z);
        acc.w = fmaf(a, mv.w, acc.w);
    }

    // ---- 16-way reduction per d-column, one float4 store per column ----
    red[tt * 32 + dc] = acc;
    __syncthreads();
    if (tid < 32) {
        float4 r = red[tid];
        #pragma unroll
        for (int s = 1; s < 16; ++s) {
            const float4 v = red[s * 32 + tid];
            r.x += v.x; r.y += v.y; r.z += v.z; r.w += v.w;
        }
        ((float4*)(context + (size_t)b * DENC + d0))[tid] = r;
    }
}

extern "C" void kernel_launch(void* const* d_in, const int* in_sizes, int n_in,
                              void* d_out, int out_size, void* d_ws, size_t ws_size,
                              hipStream_t stream) {
    const float*         q       = (const float*)d_in[0];          // att_rnn_h (64,1024)
    const float*         memory  = (const float*)d_in[1];          // (64,1024,512)
    const unsigned char* mask    = (const unsigned char*)d_in[2];  // bool (64,1024)
    const float*         mu_prev = (const float*)d_in[3];          // (64,5)
    const float*         W1      = (const float*)d_in[4];          // (1024,256)
    const float*         b1      = (const float*)d_in[5];          // (256,)
    const float*         W2      = (const float*)d_in[6];          // (256,15)
    const float*         b2      = (const float*)d_in[7];          // (15,)

    float* out   = (float*)d_out;
    float* ctx   = out;                  // context: first 64*512 floats
    float* alpha = out + NB * DENC;      // alpha_t: next 64*1024 floats

    mol_fused<<<NB * NDCH, 512, 0, stream>>>(q, W1, b1, W2, b2, mu_prev,
                                             memory, mask, alpha, ctx);
}

// Round 7
// 224.697 us; speedup vs baseline: 2.0319x; 1.0052x over previous
//
#include <hip/hip_runtime.h>
#include <cmath>

#define NB    64
#define TENC  1024
#define DENC  512
#define QDIM  1024
#define HDIM  256
#define NM    5
#define EPSF  1e-5f
#define DCH   128                 // d-columns per context block
#define NDCH  (DENC / DCH)        // 4 d-chunks -> 64*4 = 256 blocks = 1/CU

// ---------------------------------------------------------------------------
// Single fused kernel. Grid = NB * NDCH = 256 blocks (1/CU), 512 threads.
// R7 change: force memory-level parallelism. R5/R6 evidence: dur pinned at
// 77us, hbm 937 GB/s, VGPR_Count=32 -> only ~2-3 loads in flight per wave
// (32 VGPRs can't hold 8 float4 results), i.e. latency-bound by register-
// starved ILP. Fix: __launch_bounds__(512,2) (VGPR cap 256) + explicit
// group-of-8 prefetch into named registers in BOTH the W1 loop and the
// memory stream loop, so 8x16B loads are issued before any FMA consumes.
// (R3 lesson stands: no fences/atomics. R6: t-phase rotation kept, neutral.)
// ---------------------------------------------------------------------------
__global__ __launch_bounds__(512, 2) void mol_fused(
    const float* __restrict__ q,        // B x 1024
    const float* __restrict__ W1,       // 1024 x 256 (row-major)
    const float* __restrict__ b1,       // 256
    const float* __restrict__ W2,       // 256 x 15
    const float* __restrict__ b2,       // 15
    const float* __restrict__ mu_prev,  // B x 5
    const float* __restrict__ memory,   // B x T x D
    const unsigned char* __restrict__ mask, // B x T
    float* __restrict__ alpha_out,      // B x T (in d_out)
    float* __restrict__ context)        // B x DENC (in d_out)
{
    __shared__ float  q_lds[QDIM];         // 4 KB
    __shared__ float4 part8[8][64];        // 8 KB  (split-K partials for h)
    __shared__ float  h_lds[HDIM];         // 1 KB
    __shared__ float  p_part[15][16];      // split-K partials for params
    __shared__ float  p_lds[16];
    __shared__ float  stats[16];           // w[5], sigma[5], mu[5]
    __shared__ float  a_lds[TENC];         // 4 KB
    __shared__ float4 red[16 * 32];        // 8 KB

    const int b   = blockIdx.x >> 2;       // / NDCH
    const int dch = blockIdx.x & (NDCH - 1);
    const int tid = threadIdx.x;
    const int d0  = dch * DCH;

    // ---- stage q row (4 KB), float4-coalesced ----
    if (tid < 256)
        ((float4*)q_lds)[tid] = ((const float4*)(q + (size_t)b * QDIM))[tid];
    __syncthreads();

    // ---- h = relu(q @ W1 + b1): (g = k-group 0..7, c = output float4 0..63)
    //      group-of-8 prefetch: 8 x 16B W1 loads in flight per wave ----
    {
        const int g = tid >> 6;
        const int c = tid & 63;
        const float4* W1v = (const float4*)W1 + c;   // [k][64] float4, col c
        float4 acc = make_float4(0.f, 0.f, 0.f, 0.f);
        const int k0 = g << 7;                       // 128 k-rows per group
        for (int kk = 0; kk < 128; kk += 8) {
            float4 wv[8];
            float  qk[8];
            #pragma unroll
            for (int j = 0; j < 8; ++j) {
                qk[j] = q_lds[k0 + kk + j];                    // wave-broadcast
                wv[j] = W1v[(size_t)(k0 + kk + j) * 64];       // issued back-to-back
            }
            #pragma unroll
            for (int j = 0; j < 8; ++j) {
                acc.x = fmaf(qk[j], wv[j].x, acc.x);
                acc.y = fmaf(qk[j], wv[j].y, acc.y);
                acc.z = fmaf(qk[j], wv[j].z, acc.z);
                acc.w = fmaf(qk[j], wv[j].w, acc.w);
            }
        }
        part8[g][c] = acc;
    }
    __syncthreads();

    if (tid < 64) {
        float4 s = part8[0][tid];
        #pragma unroll
        for (int g = 1; g < 8; ++g) {
            const float4 v = part8[g][tid];
            s.x += v.x; s.y += v.y; s.z += v.z; s.w += v.w;
        }
        const float4 bb = ((const float4*)b1)[tid];
        float4 h;
        h.x = fmaxf(s.x + bb.x, 0.f);
        h.y = fmaxf(s.y + bb.y, 0.f);
        h.z = fmaxf(s.z + bb.z, 0.f);
        h.w = fmaxf(s.w + bb.w, 0.f);
        ((float4*)h_lds)[tid] = h;
    }
    __syncthreads();

    // ---- params = h @ W2 + b2 : 15 outputs x 16 k-groups of 16 ----
    if (tid < 240) {
        const int o  = tid >> 4;        // output 0..14
        const int kg = tid & 15;        // k-group 0..15
        float acc = 0.f;
        #pragma unroll
        for (int i = 0; i < 16; ++i) {
            const int k = kg * 16 + i;
            acc = fmaf(h_lds[k], W2[k * 15 + o], acc);
        }
        p_part[o][kg] = acc;
    }
    __syncthreads();
    if (tid < 15) {
        float acc = b2[tid];
        #pragma unroll
        for (int kg = 0; kg < 16; ++kg) acc += p_part[tid][kg];
        p_lds[tid] = acc;
    }
    __syncthreads();

    // ---- stats ----
    if (tid == 0) {
        float mx = p_lds[0];
        #pragma unroll
        for (int m = 1; m < NM; ++m) mx = fmaxf(mx, p_lds[m]);
        float e[NM], se = 0.f;
        #pragma unroll
        for (int m = 0; m < NM; ++m) { e[m] = expf(p_lds[m] - mx); se += e[m]; }
        const float inv = 1.f / se;
        #pragma unroll
        for (int m = 0; m < NM; ++m) stats[m] = e[m] * inv + EPSF;
        #pragma unroll
        for (int m = 0; m < NM; ++m) {      // sigma = softplus + eps (stable)
            const float x = p_lds[NM + m];
            stats[NM + m] = fmaxf(x, 0.f) + log1pf(expf(-fabsf(x))) + EPSF;
        }
        #pragma unroll
        for (int m = 0; m < NM; ++m) {      // mu = mu_prev + softplus(Delta)
            const float x = p_lds[2 * NM + m];
            stats[2 * NM + m] = mu_prev[b * NM + m] + fmaxf(x, 0.f) + log1pf(expf(-fabsf(x)));
        }
    }
    __syncthreads();

    // ---- alpha: 2 t-values per thread ----
    #pragma unroll
    for (int i = 0; i < 2; ++i) {
        const int t = tid + i * 512;
        const float jA = (float)t + 0.5f;
        const float jB = (float)t + 1.5f;
        float FA = 0.f, FB = 0.f;
        #pragma unroll
        for (int m = 0; m < NM; ++m) {
            const float w   = stats[m];
            const float isg = 1.f / stats[NM + m];
            const float mu  = stats[2 * NM + m];
            const float sA = 1.f / (1.f + expf(-(mu - jA) * isg));   // sigmoid
            const float sB = 1.f / (1.f + expf(-(mu - jB) * isg));
            FA += w / (1.f + sA);
            FB += w / (1.f + sB);
        }
        float a = FB - FA;
        if (a == 0.f) a = EPSF;                  // where(alpha==0, EPS)
        if (mask[(size_t)b * TENC + t]) a = 0.f; // where(mask, 0)
        a_lds[t] = a;
        if (dch == 0) alpha_out[(size_t)b * TENC + t] = a;  // coalesced
    }
    __syncthreads();

    // ---- stream this block's 512 KB slice: (tt = t-phase 0..15,
    //      dc = float4 column 0..31); per wave: 2 rows x 512 B contiguous.
    //      Group-of-8 prefetch: 8 x 16B loads (8 KB/wave) in flight before
    //      any FMA consumes -> 64 KB/CU outstanding, HBM-bound not
    //      latency-bound. t rotated by b*16 (R6, kept). ----
    const int dc = tid & 31;
    const int tt = tid >> 5;
    const int tshift = b << 4;                   // per-batch phase offset
    const float4* mem4 = (const float4*)(memory + (size_t)b * TENC * DENC)
                         + (d0 >> 2) + dc;

    float4 acc = make_float4(0.f, 0.f, 0.f, 0.f);
    for (int i = 0; i < 64; i += 8) {            // 64 t-steps per thread
        float4 mv[8];
        float  av[8];
        #pragma unroll
        for (int j = 0; j < 8; ++j) {
            const int t = ((i + j) * 16 + tt + tshift) & (TENC - 1);
            mv[j] = mem4[(size_t)t * (DENC / 4)];   // 8 loads issued together
            av[j] = a_lds[t];
        }
        #pragma unroll
        for (int j = 0; j < 8; ++j) {
            acc.x = fmaf(av[j], mv[j].x, acc.x);
            acc.y = fmaf(av[j], mv[j].y, acc.y);
            acc.z = fmaf(av[j], mv[j].z, acc.z);
            acc.w = fmaf(av[j], mv[j].w, acc.w);
        }
    }

    // ---- 16-way reduction per d-column, one float4 store per column ----
    red[tt * 32 + dc] = acc;
    __syncthreads();
    if (tid < 32) {
        float4 r = red[tid];
        #pragma unroll
        for (int s = 1; s < 16; ++s) {
            const float4 v = red[s * 32 + tid];
            r.x += v.x; r.y += v.y; r.z += v.z; r.w += v.w;
        }
        ((float4*)(context + (size_t)b * DENC + d0))[tid] = r;
    }
}

extern "C" void kernel_launch(void* const* d_in, const int* in_sizes, int n_in,
                              void* d_out, int out_size, void* d_ws, size_t ws_size,
                              hipStream_t stream) {
    const float*         q       = (const float*)d_in[0];          // att_rnn_h (64,1024)
    const float*         memory  = (const float*)d_in[1];          // (64,1024,512)
    const unsigned char* mask    = (const unsigned char*)d_in[2];  // bool (64,1024)
    const float*         mu_prev = (const float*)d_in[3];          // (64,5)
    const float*         W1      = (const float*)d_in[4];          // (1024,256)
    const float*         b1      = (const float*)d_in[5];          // (256,)
    const float*         W2      = (const float*)d_in[6];          // (256,15)
    const float*         b2      = (const float*)d_in[7];          // (15,)

    float* out   = (float*)d_out;
    float* ctx   = out;                  // context: first 64*512 floats
    float* alpha = out + NB * DENC;      // alpha_t: next 64*1024 floats

    mol_fused<<<NB * NDCH, 512, 0, stream>>>(q, W1, b1, W2, b2, mu_prev,
                                             memory, mask, alpha, ctx);
}